// Round 3
// baseline (1872.248 us; speedup 1.0000x reference)
//
#include <hip/hip_runtime.h>

// Problem constants
#define S_LEN   4096
#define D_DIM   1024
#define WIN_    256
#define STRIDE_ 128
#define GLOB_   16
#define SCALE_F 0.03125f   // 1/sqrt(1024)
#define EPS_F   1e-5f

typedef __bf16 bf16x8 __attribute__((ext_vector_type(8)));
typedef float  f32x4  __attribute__((ext_vector_type(4)));

__device__ __forceinline__ float b2f(unsigned short u) {
    union { unsigned int i; float f; } c; c.i = ((unsigned int)u) << 16; return c.f;
}
__device__ __forceinline__ unsigned short f2bf(float f) {
    union { float f; unsigned int i; } c; c.f = f;
    unsigned int u = c.i;
    u += 0x7fffu + ((u >> 16) & 1u);   // round-to-nearest-even
    return (unsigned short)(u >> 16);
}

// ---------------- block reduction helper (256 threads = 4 waves) -----------
__device__ __forceinline__ float blk_sum(float v, float* red, int tid) {
    int lane = tid & 63, wv = tid >> 6;
    #pragma unroll
    for (int m = 32; m >= 1; m >>= 1) v += __shfl_xor(v, m, 64);
    __syncthreads();                       // protect red[] reuse
    if (lane == 0) red[wv] = v;
    __syncthreads();
    return red[0] + red[1] + red[2] + red[3];
}

// ---------------- LN1 stats: mu/rstd per row (fp32 input) ------------------
__global__ __launch_bounds__(256) void ln_stats_kernel(
    const float* __restrict__ in, float* __restrict__ mu, float* __restrict__ rs) {
    __shared__ float red[4];
    int row = blockIdx.x, tid = threadIdx.x;
    size_t off = (size_t)row * D_DIM + tid * 4;
    float4 r = *(const float4*)(in + off);
    float s = blk_sum(r.x + r.y + r.z + r.w, red, tid);
    float mean = s * (1.0f / 1024.0f);
    float d0 = r.x - mean, d1 = r.y - mean, d2 = r.z - mean, d3 = r.w - mean;
    float s2 = blk_sum(d0*d0 + d1*d1 + d2*d2 + d3*d3, red, tid);
    float rstd = rsqrtf(s2 * (1.0f / 1024.0f) + EPS_F);
    if (tid == 0) { mu[row] = mean; rs[row] = rstd; }
}

// ---------------- LN2 in place: data = LN(data)*g2 + b2 (fp32) -------------
// Block-local: row r reads and writes only row r -> safe in place.
__global__ __launch_bounds__(256) void ln2_inplace_kernel(
    float* __restrict__ data, const float* __restrict__ g,
    const float* __restrict__ bb) {
    __shared__ float red[4];
    int row = blockIdx.x, tid = threadIdx.x;
    size_t off = (size_t)row * D_DIM + tid * 4;
    float4 v = *(const float4*)(data + off);
    float s = blk_sum(v.x + v.y + v.z + v.w, red, tid);
    float mean = s * (1.0f / 1024.0f);
    float d0 = v.x - mean, d1 = v.y - mean, d2 = v.z - mean, d3 = v.w - mean;
    float s2 = blk_sum(d0*d0 + d1*d1 + d2*d2 + d3*d3, red, tid);
    float rstd = rsqrtf(s2 * (1.0f / 1024.0f) + EPS_F);
    float4 gr = *(const float4*)(g  + tid * 4);
    float4 br = *(const float4*)(bb + tid * 4);
    float4 o;
    o.x = d0 * rstd * gr.x + br.x;
    o.y = d1 * rstd * gr.y + br.y;
    o.z = d2 * rstd * gr.z + br.z;
    o.w = d3 * rstd * gr.w + br.w;
    *(float4*)(data + off) = o;
}

// ---------------- GEMM: C[Mx1024] = A'[Mx1024] @ W[1024x1024] --------------
// W is K-major [k][n] row-major; in-LDS transpose to Bs[n][k].
// FUSE: A'(row,k) = (A(row,k)-mu[row])*rs[row]*g[k] + bv[k]   (LN1 fused)
// AF32/WF32: A / W stored fp32 (converted to bf16 while staging)
// EPI:  write Cres[row][col] = tok[row][col] + 0.1f*acc  (fp32 residual)
// 64x64 tile, BK=32, 4 waves x mfma_f32_16x16x32_bf16.
//   A-frag: As[m=lane&15][k=quad*8+j]; B-frag: Bs[n=lane&15][k=quad*8+j]
//   C/D:    col=lane&15, row=quad*4+r   (m89/m91/m120 verified layouts)
template <bool FUSE, bool AF32, bool WF32, bool EPI>
__global__ __launch_bounds__(256) void gemm_t(
    const float* __restrict__ A32, const unsigned short* __restrict__ A16,
    const float* __restrict__ W32, const unsigned short* __restrict__ W16,
    const float* __restrict__ mu,  const float* __restrict__ rs,
    const float* __restrict__ g,   const float* __restrict__ bv,
    unsigned short* __restrict__ C16, float* __restrict__ Cres,
    const float* __restrict__ tok) {
    const int K = 1024, N = 1024;
    __shared__ __align__(16) unsigned short As[64][40];  // +8 pad, 16B-aligned rows
    __shared__ __align__(16) unsigned short Bs[64][40];
    int tid  = threadIdx.x;
    int lane = tid & 63, wv = tid >> 6;
    int lm   = lane & 15, quad = lane >> 4;
    int m0 = blockIdx.y * 64, n0 = blockIdx.x * 64;
    int srow = tid >> 2, scg = tid & 3;        // A staging: 64 rows x 4 x 8 elems
    int bk   = tid >> 3, bn  = (tid & 7) * 8;  // B staging: 32 k x 8 n-chunks

    float amu = 0.0f, ars = 0.0f;
    if (FUSE) { amu = mu[m0 + srow]; ars = rs[m0 + srow]; }

    f32x4 acc[4] = {};

    for (int k0 = 0; k0 < K; k0 += 32) {
        // ---- stage A tile (fused LN optional), convert to bf16 ----
        float av[8];
        if (AF32) {
            const float* ap = A32 + (size_t)(m0 + srow) * K + k0 + scg * 8;
            float4 p = *(const float4*)(ap);
            float4 q = *(const float4*)(ap + 4);
            av[0]=p.x; av[1]=p.y; av[2]=p.z; av[3]=p.w;
            av[4]=q.x; av[5]=q.y; av[6]=q.z; av[7]=q.w;
        } else {
            const unsigned short* ap = A16 + (size_t)(m0 + srow) * K + k0 + scg * 8;
            union { uint4 u; unsigned short s[8]; } r; r.u = *(const uint4*)ap;
            #pragma unroll
            for (int e = 0; e < 8; ++e) av[e] = b2f(r.s[e]);
        }
        if (FUSE) {
            const float* gp = g  + k0 + scg * 8;
            const float* bp = bv + k0 + scg * 8;
            float4 g0 = *(const float4*)gp, g1v = *(const float4*)(gp + 4);
            float4 b0 = *(const float4*)bp, b1v = *(const float4*)(bp + 4);
            float gg[8] = {g0.x,g0.y,g0.z,g0.w,g1v.x,g1v.y,g1v.z,g1v.w};
            float bbv[8] = {b0.x,b0.y,b0.z,b0.w,b1v.x,b1v.y,b1v.z,b1v.w};
            #pragma unroll
            for (int e = 0; e < 8; ++e)
                av[e] = (av[e] - amu) * ars * gg[e] + bbv[e];
        }
        {
            unsigned short ou[8];
            #pragma unroll
            for (int e = 0; e < 8; ++e) ou[e] = f2bf(av[e]);
            union { uint4 u; unsigned short s[8]; } w;
            #pragma unroll
            for (int e = 0; e < 8; ++e) w.s[e] = ou[e];
            *(uint4*)&As[srow][scg * 8] = w.u;
        }
        // ---- stage B tile with in-LDS transpose, convert to bf16 ----
        if (WF32) {
            const float* wp = W32 + (size_t)(k0 + bk) * N + n0 + bn;
            float4 p = *(const float4*)wp, q = *(const float4*)(wp + 4);
            float wvv[8] = {p.x,p.y,p.z,p.w,q.x,q.y,q.z,q.w};
            #pragma unroll
            for (int e = 0; e < 8; ++e) Bs[bn + e][bk] = f2bf(wvv[e]);
        } else {
            const unsigned short* wp = W16 + (size_t)(k0 + bk) * N + n0 + bn;
            union { uint4 u; unsigned short s[8]; } r; r.u = *(const uint4*)wp;
            #pragma unroll
            for (int e = 0; e < 8; ++e) Bs[bn + e][bk] = r.s[e];
        }
        __syncthreads();
        bf16x8 a = *(const bf16x8*)&As[wv * 16 + lm][quad * 8];
        #pragma unroll
        for (int t = 0; t < 4; ++t) {
            bf16x8 b = *(const bf16x8*)&Bs[t * 16 + lm][quad * 8];
            acc[t] = __builtin_amdgcn_mfma_f32_16x16x32_bf16(a, b, acc[t], 0, 0, 0);
        }
        __syncthreads();
    }
    #pragma unroll
    for (int t = 0; t < 4; ++t) {
        int col = n0 + t * 16 + lm;
        #pragma unroll
        for (int r = 0; r < 4; ++r) {
            int row = m0 + wv * 16 + quad * 4 + r;
            size_t idx = (size_t)row * N + col;
            if (EPI) Cres[idx] = tok[idx] + 0.1f * acc[t][r];
            else     C16[idx]  = f2bf(acc[t][r]);
        }
    }
}

// ---------------- Sparse attention: one block per (b, query i) -------------
// Q,K bf16. "V" recomputed on the fly: x'_j = (tokens_j - mu_j)*rs_j*g1 + b1.
// Output attnX = softmax-weighted sum of x' rows, bf16, written over Q.
__global__ __launch_bounds__(256) void attn_kernel(
    const unsigned short* __restrict__ Q, const unsigned short* __restrict__ Km,
    const float* __restrict__ tok, const float* __restrict__ mu,
    const float* __restrict__ rs, const float* __restrict__ g1,
    const float* __restrict__ b1, unsigned short* __restrict__ Ao) {
    __shared__ float qs[1024];
    __shared__ float sc[336];
    __shared__ int   kidx[336];
    __shared__ float mus[336], rss[336];
    __shared__ float red[8];
    int bi = blockIdx.x;
    int i  = bi & (S_LEN - 1);
    int tid = threadIdx.x, lane = tid & 63, wv = tid >> 6;
    size_t qoff = (size_t)bi * D_DIM;
    size_t base = (size_t)(bi - i) * D_DIM;   // b * S * D (element offset)
    int row0 = bi - i;                         // b * S

    {   // stage Q row in fp32
        ushort4 r = *(const ushort4*)(Q + qoff + tid * 4);
        qs[tid*4+0] = b2f(r.x); qs[tid*4+1] = b2f(r.y);
        qs[tid*4+2] = b2f(r.z); qs[tid*4+3] = b2f(r.w);
    }
    // enumerate allowed keys exactly once:
    //  window [jw0..i]; strided j=i-128t (t>=2, j>=16); global j in [0, min(16,jw0))
    int jw0 = i - (WIN_ - 1); if (jw0 < 0) jw0 = 0;
    int cw = i - jw0 + 1;
    int cs = (i >= 272) ? ((i - 16) / 128 - 1) : 0;
    int cg = (jw0 < GLOB_) ? jw0 : GLOB_;
    int total = cw + cs + cg;
    for (int l = tid; l < total; l += 256) {
        int j;
        if (l < cw)           j = jw0 + l;
        else if (l < cw + cs) j = i - 128 * (2 + (l - cw));
        else                  j = l - (cw + cs);
        kidx[l] = j;
        mus[l]  = mu[row0 + j];
        rss[l]  = rs[row0 + j];
    }
    __syncthreads();

    // scores: one wave per key, lanes split H
    for (int l = wv; l < total; l += 4) {
        const unsigned short* kr = Km + base + (size_t)kidx[l] * D_DIM;
        float p = 0.0f;
        #pragma unroll
        for (int c = 0; c < 16; ++c)
            p += qs[c * 64 + lane] * b2f(kr[c * 64 + lane]);
        #pragma unroll
        for (int m = 32; m >= 1; m >>= 1) p += __shfl_xor(p, m, 64);
        if (lane == 0) sc[l] = p * SCALE_F;
    }
    __syncthreads();

    // softmax over sc[0..total)
    float mx = -1e30f;
    for (int l = tid; l < total; l += 256) mx = fmaxf(mx, sc[l]);
    #pragma unroll
    for (int m = 32; m >= 1; m >>= 1) mx = fmaxf(mx, __shfl_xor(mx, m, 64));
    if (lane == 0) red[wv] = mx;
    __syncthreads();
    mx = fmaxf(fmaxf(red[0], red[1]), fmaxf(red[2], red[3]));

    float sm = 0.0f;
    for (int l = tid; l < total; l += 256) {
        float e = __expf(sc[l] - mx);
        sc[l] = e;
        sm += e;
    }
    #pragma unroll
    for (int m = 32; m >= 1; m >>= 1) sm += __shfl_xor(sm, m, 64);
    if (lane == 0) red[4 + wv] = sm;
    __syncthreads();
    float inv = 1.0f / (red[4] + red[5] + red[6] + red[7]);

    // weighted x' accumulation: thread owns 4 consecutive d
    int dbase = tid * 4;
    float4 g4 = *(const float4*)(g1 + dbase);
    float4 b4 = *(const float4*)(b1 + dbase);
    float a0 = 0, a1 = 0, a2 = 0, a3 = 0;
    for (int l = 0; l < total; ++l) {
        float w = sc[l];
        float m = mus[l], r_ = rss[l];
        float4 tv = *(const float4*)(tok + base + (size_t)kidx[l] * D_DIM + dbase);
        a0 += w * ((tv.x - m) * r_ * g4.x + b4.x);
        a1 += w * ((tv.y - m) * r_ * g4.y + b4.y);
        a2 += w * ((tv.z - m) * r_ * g4.z + b4.z);
        a3 += w * ((tv.w - m) * r_ * g4.w + b4.w);
    }
    ushort4 o;
    o.x = f2bf(a0 * inv); o.y = f2bf(a1 * inv);
    o.z = f2bf(a2 * inv); o.w = f2bf(a3 * inv);
    *(ushort4*)(Ao + qoff + dbase) = o;
}

// ---------------------------------------------------------------------------
extern "C" void kernel_launch(void* const* d_in, const int* in_sizes, int n_in,
                              void* d_out, int out_size, void* d_ws, size_t ws_size,
                              hipStream_t stream) {
    const float* tokens = (const float*)d_in[0];
    const float* Wq = (const float*)d_in[1];
    const float* Wk = (const float*)d_in[2];
    const float* Wv = (const float*)d_in[3];
    const float* Wo = (const float*)d_in[4];
    const float* g1 = (const float*)d_in[5];
    const float* b1 = (const float*)d_in[6];
    const float* g2 = (const float*)d_in[7];
    const float* b2 = (const float*)d_in[8];
    float* out = (float*)d_out;
    char* ws = (char*)d_ws;

    // Workspace layout (36 MB total):
    //   [0, 64KB)       mu   (16384 f32)
    //   [64KB, 128KB)   rs   (16384 f32)
    //   [2MB, 4MB)      Wfused = bf16(Wv@Wo)  [1024x1024]
    //   [4MB, 36MB)     Q bf16 -> attnX (in place)
    // d_out (64 MB fp32): first 32MB holds K bf16 until attention is done;
    // then the out-GEMM overwrites all of d_out with tokens + 0.1*(attnX@Wfused)
    // in fp32; LN2 runs in place (block-local rows).
    const size_t MB = 1048576;
    float* mu = (float*)(ws);
    float* rs = (float*)(ws + 65536);
    unsigned short* Wfused = (unsigned short*)(ws + 2 * MB);
    unsigned short* Qb     = (unsigned short*)(ws + 4 * MB);
    unsigned short* Kb     = (unsigned short*)d_out;   // bf16 K in d_out[0:32MB)
    unsigned short* attnX  = Qb;                       // in place over Q

    dim3 b256(256);
    const int ROWS = 4 * S_LEN;           // 16384

    ln_stats_kernel<<<ROWS, b256, 0, stream>>>(tokens, mu, rs);

    // Wfused = Wv @ Wo  (1024x1024x1024, fp32 in, bf16 out)
    dim3 gsmall(16, 16);
    gemm_t<false, true, true, false><<<gsmall, b256, 0, stream>>>(
        Wv, nullptr, Wo, nullptr, nullptr, nullptr, nullptr, nullptr,
        Wfused, nullptr, nullptr);

    dim3 gg(16, 256);                     // N/64 x M/64
    // Q = LN1(tokens) @ Wq ; K = LN1(tokens) @ Wk   (fp32 in, bf16 out)
    gemm_t<true, true, true, false><<<gg, b256, 0, stream>>>(
        tokens, nullptr, Wq, nullptr, mu, rs, g1, b1, Qb, nullptr, nullptr);
    gemm_t<true, true, true, false><<<gg, b256, 0, stream>>>(
        tokens, nullptr, Wk, nullptr, mu, rs, g1, b1, Kb, nullptr, nullptr);

    // attnX = softmax(sparse(QK^T)) . LN1(tokens)   (writes over Q)
    attn_kernel<<<ROWS, b256, 0, stream>>>(Qb, Kb, tokens, mu, rs, g1, b1, attnX);

    // d_out = tokens + 0.1 * (attnX @ Wfused)   (bf16 in, fp32 residual out)
    gemm_t<false, false, false, true><<<gg, b256, 0, stream>>>(
        nullptr, attnX, nullptr, Wfused, nullptr, nullptr, nullptr, nullptr,
        nullptr, out, tokens);

    // out = LN2(out)  (in place, block-local)
    ln2_inplace_kernel<<<ROWS, b256, 0, stream>>>(out, g2, b2);
}

// Round 4
// 1290.016 us; speedup vs baseline: 1.4513x; 1.4513x over previous
//
#include <hip/hip_runtime.h>

// Problem constants
#define S_LEN   4096
#define D_DIM   1024
#define WIN_    256
#define STRIDE_ 128
#define GLOB_   16
#define SCALE_F 0.03125f   // 1/sqrt(1024)
#define EPS_F   1e-5f

typedef __bf16 bf16x8 __attribute__((ext_vector_type(8)));
typedef float  f32x4  __attribute__((ext_vector_type(4)));

__device__ __forceinline__ float b2f(unsigned short u) {
    union { unsigned int i; float f; } c; c.i = ((unsigned int)u) << 16; return c.f;
}
__device__ __forceinline__ float bflo(unsigned int w) {
    union { unsigned int i; float f; } c; c.i = w << 16; return c.f;
}
__device__ __forceinline__ float bfhi(unsigned int w) {
    union { unsigned int i; float f; } c; c.i = w & 0xffff0000u; return c.f;
}
__device__ __forceinline__ unsigned short f2bf(float f) {
    union { float f; unsigned int i; } c; c.f = f;
    unsigned int u = c.i;
    u += 0x7fffu + ((u >> 16) & 1u);   // round-to-nearest-even
    return (unsigned short)(u >> 16);
}

// async global->LDS, 16B per lane.  HW dest = wave-uniform base + lane*16;
// we pass per-lane ptrs laid out in exactly that order (guide m104/m108).
__device__ __forceinline__ void gld_lds16(const void* g, void* l) {
    __builtin_amdgcn_global_load_lds(
        (const __attribute__((address_space(1))) unsigned int*)g,
        (__attribute__((address_space(3))) unsigned int*)l, 16, 0, 0);
}

// ---------------- block reduction helper (256 threads = 4 waves) -----------
__device__ __forceinline__ float blk_sum(float v, float* red, int tid) {
    int lane = tid & 63, wv = tid >> 6;
    #pragma unroll
    for (int m = 32; m >= 1; m >>= 1) v += __shfl_xor(v, m, 64);
    __syncthreads();
    if (lane == 0) red[wv] = v;
    __syncthreads();
    return red[0] + red[1] + red[2] + red[3];
}

// ---------------- LN1 full: mu/rs + xb = bf16(LN(tok)*g1+b1) ---------------
__global__ __launch_bounds__(256) void ln_full_kernel(
    const float* __restrict__ in, float* __restrict__ mu, float* __restrict__ rs,
    const float* __restrict__ g, const float* __restrict__ bb,
    unsigned short* __restrict__ xb) {
    __shared__ float red[4];
    int row = blockIdx.x, tid = threadIdx.x;
    size_t off = (size_t)row * D_DIM + tid * 4;
    float4 r = *(const float4*)(in + off);
    float s = blk_sum(r.x + r.y + r.z + r.w, red, tid);
    float mean = s * (1.0f / 1024.0f);
    float d0 = r.x - mean, d1 = r.y - mean, d2 = r.z - mean, d3 = r.w - mean;
    float s2 = blk_sum(d0*d0 + d1*d1 + d2*d2 + d3*d3, red, tid);
    float rstd = rsqrtf(s2 * (1.0f / 1024.0f) + EPS_F);
    if (tid == 0) { mu[row] = mean; rs[row] = rstd; }
    float4 gr = *(const float4*)(g  + tid * 4);
    float4 br = *(const float4*)(bb + tid * 4);
    ushort4 o;
    o.x = f2bf(d0 * rstd * gr.x + br.x);
    o.y = f2bf(d1 * rstd * gr.y + br.y);
    o.z = f2bf(d2 * rstd * gr.z + br.z);
    o.w = f2bf(d3 * rstd * gr.w + br.w);
    *(ushort4*)(xb + off) = o;
}

// ---------------- LN2 in place (fp32, block-local rows) --------------------
__global__ __launch_bounds__(256) void ln2_inplace_kernel(
    float* __restrict__ data, const float* __restrict__ g,
    const float* __restrict__ bb) {
    __shared__ float red[4];
    int row = blockIdx.x, tid = threadIdx.x;
    size_t off = (size_t)row * D_DIM + tid * 4;
    float4 v = *(const float4*)(data + off);
    float s = blk_sum(v.x + v.y + v.z + v.w, red, tid);
    float mean = s * (1.0f / 1024.0f);
    float d0 = v.x - mean, d1 = v.y - mean, d2 = v.z - mean, d3 = v.w - mean;
    float s2 = blk_sum(d0*d0 + d1*d1 + d2*d2 + d3*d3, red, tid);
    float rstd = rsqrtf(s2 * (1.0f / 1024.0f) + EPS_F);
    float4 gr = *(const float4*)(g  + tid * 4);
    float4 br = *(const float4*)(bb + tid * 4);
    float4 o;
    o.x = d0 * rstd * gr.x + br.x;
    o.y = d1 * rstd * gr.y + br.y;
    o.z = d2 * rstd * gr.z + br.z;
    o.w = d3 * rstd * gr.w + br.w;
    *(float4*)(data + off) = o;
}

// ---------------- transpose+convert: fp32 [1024][1024] -> bf16 T -----------
__global__ __launch_bounds__(256) void transpose_cvt(
    const float* __restrict__ in, unsigned short* __restrict__ outp) {
    __shared__ unsigned short tile[32][33];
    int tid = threadIdx.x;
    int tx = tid & 31, ty = tid >> 5;          // 32 x 8
    int bx = blockIdx.x * 32, by = blockIdx.y * 32;
    #pragma unroll
    for (int r = 0; r < 32; r += 8)
        tile[ty + r][tx] = f2bf(in[(size_t)(by + ty + r) * 1024 + bx + tx]);
    __syncthreads();
    #pragma unroll
    for (int r = 0; r < 32; r += 8)
        outp[(size_t)(bx + ty + r) * 1024 + by + tx] = tile[tx][ty + r];
}

// ---------------- bf16 1024x1024 transpose ---------------------------------
__global__ __launch_bounds__(256) void transpose1024(
    const unsigned short* __restrict__ in, unsigned short* __restrict__ outp) {
    __shared__ unsigned short tile[32][33];
    int tid = threadIdx.x;
    int tx = tid & 31, ty = tid >> 5;
    int bx = blockIdx.x * 32, by = blockIdx.y * 32;
    #pragma unroll
    for (int r = 0; r < 32; r += 8)
        tile[ty + r][tx] = in[(size_t)(by + ty + r) * 1024 + bx + tx];
    __syncthreads();
    #pragma unroll
    for (int r = 0; r < 32; r += 8)
        outp[(size_t)(bx + ty + r) * 1024 + by + tx] = tile[tx][ty + r];
}

// ---------------- small GEMM (round-3 proven): C = A32 @ W32, bf16 out -----
__global__ __launch_bounds__(256) void gemm_small(
    const float* __restrict__ A32, const float* __restrict__ W32,
    unsigned short* __restrict__ C16) {
    const int K = 1024, N = 1024;
    __shared__ __align__(16) unsigned short As[64][40];
    __shared__ __align__(16) unsigned short Bs[64][40];
    int tid  = threadIdx.x;
    int lane = tid & 63, wv = tid >> 6;
    int lm   = lane & 15, quad = lane >> 4;
    int m0 = blockIdx.y * 64, n0 = blockIdx.x * 64;
    int srow = tid >> 2, scg = tid & 3;
    int bk   = tid >> 3, bn  = (tid & 7) * 8;

    f32x4 acc[4] = {};
    for (int k0 = 0; k0 < K; k0 += 32) {
        const float* ap = A32 + (size_t)(m0 + srow) * K + k0 + scg * 8;
        float4 p = *(const float4*)(ap);
        float4 q = *(const float4*)(ap + 4);
        union { uint4 u; unsigned short s[8]; } w;
        w.s[0]=f2bf(p.x); w.s[1]=f2bf(p.y); w.s[2]=f2bf(p.z); w.s[3]=f2bf(p.w);
        w.s[4]=f2bf(q.x); w.s[5]=f2bf(q.y); w.s[6]=f2bf(q.z); w.s[7]=f2bf(q.w);
        *(uint4*)&As[srow][scg * 8] = w.u;

        const float* wp = W32 + (size_t)(k0 + bk) * N + n0 + bn;
        float4 a = *(const float4*)wp, b = *(const float4*)(wp + 4);
        float wvv[8] = {a.x,a.y,a.z,a.w,b.x,b.y,b.z,b.w};
        #pragma unroll
        for (int e = 0; e < 8; ++e) Bs[bn + e][bk] = f2bf(wvv[e]);
        __syncthreads();
        bf16x8 af = *(const bf16x8*)&As[wv * 16 + lm][quad * 8];
        #pragma unroll
        for (int t = 0; t < 4; ++t) {
            bf16x8 bfr = *(const bf16x8*)&Bs[t * 16 + lm][quad * 8];
            acc[t] = __builtin_amdgcn_mfma_f32_16x16x32_bf16(af, bfr, acc[t], 0, 0, 0);
        }
        __syncthreads();
    }
    #pragma unroll
    for (int t = 0; t < 4; ++t) {
        int col = n0 + t * 16 + lm;
        #pragma unroll
        for (int r = 0; r < 4; ++r) {
            int row = m0 + wv * 16 + quad * 4 + r;
            C16[(size_t)row * N + col] = f2bf(acc[t][r]);
        }
    }
}

// ---------------- m97-style 128x128 GEMM: C = A[bf16] @ BT[bf16]^T ---------
// A [M][1024], BT [1024][1024] n-major.  BK=32, 4 waves in 2x2, each wave
// 64x64 (4x4 16x16x32 frags).  LDS layout [k-octet][row][8] so that
// global_load_lds lane order == LDS contiguous order (no padding allowed).
// EPI: Cres[idx] = tok[idx] + 0.1f*acc (fp32); else bf16 store.
template <bool EPI>
__global__ __launch_bounds__(256) void gemm128(
    const unsigned short* __restrict__ A, const unsigned short* __restrict__ BT,
    unsigned short* __restrict__ C16, float* __restrict__ Cres,
    const float* __restrict__ tok) {
    const int K = 1024, N = 1024;
    __shared__ __align__(16) unsigned short As[4096];  // 4 octets x 128 rows x 8
    __shared__ __align__(16) unsigned short Bs[4096];
    int tid = threadIdx.x, lane = tid & 63, wv = tid >> 6;
    int lm = lane & 15, quad = lane >> 4;
    int wr = wv >> 1, wc = wv & 1;
    int m0 = blockIdx.y * 128, n0 = blockIdx.x * 128;

    f32x4 acc[4][4] = {};

    const unsigned short* ga0 = A  + (size_t)(m0 + lane) * K + wv * 8;
    const unsigned short* ga1 = A  + (size_t)(m0 + 64 + lane) * K + wv * 8;
    const unsigned short* gb0 = BT + (size_t)(n0 + lane) * K + wv * 8;
    const unsigned short* gb1 = BT + (size_t)(n0 + 64 + lane) * K + wv * 8;
    unsigned short* la0 = &As[wv * 1024 + lane * 8];
    unsigned short* la1 = &As[wv * 1024 + 512 + lane * 8];
    unsigned short* lb0 = &Bs[wv * 1024 + lane * 8];
    unsigned short* lb1 = &Bs[wv * 1024 + 512 + lane * 8];

    for (int k0 = 0; k0 < K; k0 += 32) {
        gld_lds16(ga0 + k0, la0);
        gld_lds16(ga1 + k0, la1);
        gld_lds16(gb0 + k0, lb0);
        gld_lds16(gb1 + k0, lb1);
        __syncthreads();
        bf16x8 af[4], bfr[4];
        #pragma unroll
        for (int t = 0; t < 4; ++t) {
            af[t]  = *(const bf16x8*)&As[quad * 1024 + (wr * 64 + t * 16 + lm) * 8];
            bfr[t] = *(const bf16x8*)&Bs[quad * 1024 + (wc * 64 + t * 16 + lm) * 8];
        }
        #pragma unroll
        for (int mt = 0; mt < 4; ++mt)
            #pragma unroll
            for (int nt = 0; nt < 4; ++nt)
                acc[mt][nt] = __builtin_amdgcn_mfma_f32_16x16x32_bf16(
                    af[mt], bfr[nt], acc[mt][nt], 0, 0, 0);
        __syncthreads();
    }
    #pragma unroll
    for (int mt = 0; mt < 4; ++mt) {
        #pragma unroll
        for (int nt = 0; nt < 4; ++nt) {
            int col = n0 + wc * 64 + nt * 16 + lm;
            #pragma unroll
            for (int r = 0; r < 4; ++r) {
                int row = m0 + wr * 64 + mt * 16 + quad * 4 + r;
                size_t idx = (size_t)row * N + col;
                if (EPI) Cres[idx] = tok[idx] + 0.1f * acc[mt][nt][r];
                else     C16[idx]  = f2bf(acc[mt][nt][r]);
            }
        }
    }
}

// ---------------- Sparse attention: one block per (b, query i) -------------
// Q,K,X all bf16.  X = LN1 rows (xb).  attnX = softmax(QK^T_sparse) @ X,
// written bf16 over Q.
__global__ __launch_bounds__(256) void attn_kernel(
    const unsigned short* __restrict__ Q, const unsigned short* __restrict__ Km,
    const unsigned short* __restrict__ X, unsigned short* __restrict__ Ao) {
    __shared__ float sc[336];
    __shared__ int   kidx[336];
    __shared__ float red[8];
    int bi = blockIdx.x;
    int i  = bi & (S_LEN - 1);
    int tid = threadIdx.x, lane = tid & 63, wv = tid >> 6;
    size_t qoff = (size_t)bi * D_DIM;
    size_t base = (size_t)(bi - i) * D_DIM;

    // Q fragment in registers: lane owns elements [lane*16, lane*16+16)
    float qr[16];
    {
        const unsigned short* qp = Q + qoff + lane * 16;
        union { uint4 u; unsigned int w[4]; } r0, r1;
        r0.u = *(const uint4*)qp;
        r1.u = *(const uint4*)(qp + 8);
        #pragma unroll
        for (int e = 0; e < 4; ++e) {
            qr[2*e]     = bflo(r0.w[e]); qr[2*e + 1] = bfhi(r0.w[e]);
            qr[8 + 2*e] = bflo(r1.w[e]); qr[9 + 2*e] = bfhi(r1.w[e]);
        }
    }
    // enumerate allowed keys exactly once
    int jw0 = i - (WIN_ - 1); if (jw0 < 0) jw0 = 0;
    int cw = i - jw0 + 1;
    int cs = (i >= 272) ? ((i - 16) / 128 - 1) : 0;
    int cg = (jw0 < GLOB_) ? jw0 : GLOB_;
    int total = cw + cs + cg;
    for (int l = tid; l < total; l += 256) {
        int j;
        if (l < cw)           j = jw0 + l;
        else if (l < cw + cs) j = i - 128 * (2 + (l - cw));
        else                  j = l - (cw + cs);
        kidx[l] = j;
    }
    __syncthreads();

    // scores: one wave per key
    for (int l = wv; l < total; l += 4) {
        const unsigned short* kr = Km + base + (size_t)kidx[l] * D_DIM + lane * 16;
        union { uint4 u; unsigned int w[4]; } k0, k1;
        k0.u = *(const uint4*)kr;
        k1.u = *(const uint4*)(kr + 8);
        float p = 0.0f;
        #pragma unroll
        for (int e = 0; e < 4; ++e) {
            p += qr[2*e]     * bflo(k0.w[e]) + qr[2*e + 1] * bfhi(k0.w[e]);
            p += qr[8 + 2*e] * bflo(k1.w[e]) + qr[9 + 2*e] * bfhi(k1.w[e]);
        }
        #pragma unroll
        for (int m = 32; m >= 1; m >>= 1) p += __shfl_xor(p, m, 64);
        if (lane == 0) sc[l] = p * SCALE_F;
    }
    __syncthreads();

    // softmax
    float mx = -1e30f;
    for (int l = tid; l < total; l += 256) mx = fmaxf(mx, sc[l]);
    #pragma unroll
    for (int m = 32; m >= 1; m >>= 1) mx = fmaxf(mx, __shfl_xor(mx, m, 64));
    if (lane == 0) red[wv] = mx;
    __syncthreads();
    mx = fmaxf(fmaxf(red[0], red[1]), fmaxf(red[2], red[3]));

    float sm = 0.0f;
    for (int l = tid; l < total; l += 256) {
        float e = __expf(sc[l] - mx);
        sc[l] = e;
        sm += e;
    }
    #pragma unroll
    for (int m = 32; m >= 1; m >>= 1) sm += __shfl_xor(sm, m, 64);
    if (lane == 0) red[4 + wv] = sm;
    __syncthreads();
    float inv = 1.0f / (red[4] + red[5] + red[6] + red[7]);

    // weighted X accumulation: thread owns 4 consecutive d
    int dbase = tid * 4;
    float a0 = 0, a1 = 0, a2 = 0, a3 = 0;
    const unsigned short* xb = X + base + dbase;
    #pragma unroll 2
    for (int l = 0; l < total; ++l) {
        float w = sc[l];
        const unsigned short* xr = xb + (size_t)kidx[l] * D_DIM;
        uint2 r = *(const uint2*)xr;
        a0 += w * bflo(r.x); a1 += w * bfhi(r.x);
        a2 += w * bflo(r.y); a3 += w * bfhi(r.y);
    }
    ushort4 o;
    o.x = f2bf(a0 * inv); o.y = f2bf(a1 * inv);
    o.z = f2bf(a2 * inv); o.w = f2bf(a3 * inv);
    *(ushort4*)(Ao + qoff + dbase) = o;
}

// ---------------------------------------------------------------------------
extern "C" void kernel_launch(void* const* d_in, const int* in_sizes, int n_in,
                              void* d_out, int out_size, void* d_ws, size_t ws_size,
                              hipStream_t stream) {
    const float* tokens = (const float*)d_in[0];
    const float* Wq = (const float*)d_in[1];
    const float* Wk = (const float*)d_in[2];
    const float* Wv = (const float*)d_in[3];
    const float* Wo = (const float*)d_in[4];
    const float* g1 = (const float*)d_in[5];
    const float* b1 = (const float*)d_in[6];
    const float* g2 = (const float*)d_in[7];
    const float* b2 = (const float*)d_in[8];
    float* out = (float*)d_out;
    char* ws = (char*)d_ws;

    // d_out (64MB fp32) doubles as scratch before the final out-GEMM:
    //   xb bf16 @ d_out[0:32MB)   (LN1 rows; dead after attention)
    //   K  bf16 @ d_out[32:64MB)  (dead after attention)
    // ws (41MB):
    //   mu @0 (64KB), rs @64KB, WqT @1MB, WkT @3MB, Wfused @5MB, WfT @7MB,
    //   Q bf16 @9MB (32MB) -> attnX in place
    const size_t MB = 1048576;
    float* mu = (float*)(ws);
    float* rs = (float*)(ws + 65536);
    unsigned short* WqT    = (unsigned short*)(ws + 1 * MB);
    unsigned short* WkT    = (unsigned short*)(ws + 3 * MB);
    unsigned short* Wfused = (unsigned short*)(ws + 5 * MB);
    unsigned short* WfT    = (unsigned short*)(ws + 7 * MB);
    unsigned short* Qb     = (unsigned short*)(ws + 9 * MB);
    unsigned short* xb     = (unsigned short*)d_out;
    unsigned short* Kb     = (unsigned short*)d_out + 16777216;
    unsigned short* attnX  = Qb;

    dim3 b256(256);
    const int ROWS = 4 * S_LEN;           // 16384
    dim3 tg(32, 32);
    dim3 gsmall(16, 16);
    dim3 g128(8, 128);                    // N/128 x M/128

    // 1. LN1: stats + xb
    ln_full_kernel<<<ROWS, b256, 0, stream>>>(tokens, mu, rs, g1, b1, xb);
    // 2. weight prep (bf16, transposed to n-major)
    transpose_cvt<<<tg, b256, 0, stream>>>(Wq, WqT);
    transpose_cvt<<<tg, b256, 0, stream>>>(Wk, WkT);
    gemm_small<<<gsmall, b256, 0, stream>>>(Wv, Wo, Wfused);
    transpose1024<<<tg, b256, 0, stream>>>(Wfused, WfT);
    // 3. Q = xb@Wq, K = xb@Wk
    gemm128<false><<<g128, b256, 0, stream>>>(xb, WqT, Qb, nullptr, nullptr);
    gemm128<false><<<g128, b256, 0, stream>>>(xb, WkT, Kb, nullptr, nullptr);
    // 4. sparse attention (attnX over Q)
    attn_kernel<<<ROWS, b256, 0, stream>>>(Qb, Kb, xb, attnX);
    // 5. out = tokens + 0.1*(attnX @ Wfused)  (overwrites all of d_out)
    gemm128<true><<<g128, b256, 0, stream>>>(attnX, WfT, nullptr, out, tokens);
    // 6. LN2 in place
    ln2_inplace_kernel<<<ROWS, b256, 0, stream>>>(out, g2, b2);
}

// Round 5
// 934.153 us; speedup vs baseline: 2.0042x; 1.3809x over previous
//
#include <hip/hip_runtime.h>

// Problem constants
#define S_LEN   4096
#define D_DIM   1024
#define WIN_    256
#define STRIDE_ 128
#define GLOB_   16
#define SCALE_F 0.03125f   // 1/sqrt(1024)
#define EPS_F   1e-5f

typedef __bf16 bf16x8 __attribute__((ext_vector_type(8)));
typedef float  f32x4  __attribute__((ext_vector_type(4)));

__device__ __forceinline__ float b2f(unsigned short u) {
    union { unsigned int i; float f; } c; c.i = ((unsigned int)u) << 16; return c.f;
}
__device__ __forceinline__ unsigned short f2bf(float f) {
    union { float f; unsigned int i; } c; c.f = f;
    unsigned int u = c.i;
    u += 0x7fffu + ((u >> 16) & 1u);   // round-to-nearest-even
    return (unsigned short)(u >> 16);
}

// async global->LDS, 16B per lane (dest = wave-uniform base + lane*16)
__device__ __forceinline__ void gld_lds16(const void* g, void* l) {
    __builtin_amdgcn_global_load_lds(
        (const __attribute__((address_space(1))) unsigned int*)g,
        (__attribute__((address_space(3))) unsigned int*)l, 16, 0, 0);
}

// ---------------- block reduction helper (256 threads = 4 waves) -----------
__device__ __forceinline__ float blk_sum(float v, float* red, int tid) {
    int lane = tid & 63, wv = tid >> 6;
    #pragma unroll
    for (int m = 32; m >= 1; m >>= 1) v += __shfl_xor(v, m, 64);
    __syncthreads();
    if (lane == 0) red[wv] = v;
    __syncthreads();
    return red[0] + red[1] + red[2] + red[3];
}

// ---------------- LN1 full: mu/rs + xb = bf16(LN(tok)*g1+b1) ---------------
__global__ __launch_bounds__(256) void ln_full_kernel(
    const float* __restrict__ in, float* __restrict__ mu, float* __restrict__ rs,
    const float* __restrict__ g, const float* __restrict__ bb,
    unsigned short* __restrict__ xb) {
    __shared__ float red[4];
    int row = blockIdx.x, tid = threadIdx.x;
    size_t off = (size_t)row * D_DIM + tid * 4;
    float4 r = *(const float4*)(in + off);
    float s = blk_sum(r.x + r.y + r.z + r.w, red, tid);
    float mean = s * (1.0f / 1024.0f);
    float d0 = r.x - mean, d1 = r.y - mean, d2 = r.z - mean, d3 = r.w - mean;
    float s2 = blk_sum(d0*d0 + d1*d1 + d2*d2 + d3*d3, red, tid);
    float rstd = rsqrtf(s2 * (1.0f / 1024.0f) + EPS_F);
    if (tid == 0) { mu[row] = mean; rs[row] = rstd; }
    float4 gr = *(const float4*)(g  + tid * 4);
    float4 br = *(const float4*)(bb + tid * 4);
    ushort4 o;
    o.x = f2bf(d0 * rstd * gr.x + br.x);
    o.y = f2bf(d1 * rstd * gr.y + br.y);
    o.z = f2bf(d2 * rstd * gr.z + br.z);
    o.w = f2bf(d3 * rstd * gr.w + br.w);
    *(ushort4*)(xb + off) = o;
}

// ---------------- LN2 in place (fp32, block-local rows) --------------------
__global__ __launch_bounds__(256) void ln2_inplace_kernel(
    float* __restrict__ data, const float* __restrict__ g,
    const float* __restrict__ bb) {
    __shared__ float red[4];
    int row = blockIdx.x, tid = threadIdx.x;
    size_t off = (size_t)row * D_DIM + tid * 4;
    float4 v = *(const float4*)(data + off);
    float s = blk_sum(v.x + v.y + v.z + v.w, red, tid);
    float mean = s * (1.0f / 1024.0f);
    float d0 = v.x - mean, d1 = v.y - mean, d2 = v.z - mean, d3 = v.w - mean;
    float s2 = blk_sum(d0*d0 + d1*d1 + d2*d2 + d3*d3, red, tid);
    float rstd = rsqrtf(s2 * (1.0f / 1024.0f) + EPS_F);
    float4 gr = *(const float4*)(g  + tid * 4);
    float4 br = *(const float4*)(bb + tid * 4);
    float4 o;
    o.x = d0 * rstd * gr.x + br.x;
    o.y = d1 * rstd * gr.y + br.y;
    o.z = d2 * rstd * gr.z + br.z;
    o.w = d3 * rstd * gr.w + br.w;
    *(float4*)(data + off) = o;
}

// ---------------- transpose+convert: fp32 [1024][1024] -> bf16 T -----------
__global__ __launch_bounds__(256) void transpose_cvt(
    const float* __restrict__ in, unsigned short* __restrict__ outp) {
    __shared__ unsigned short tile[32][33];
    int tid = threadIdx.x;
    int tx = tid & 31, ty = tid >> 5;          // 32 x 8
    int bx = blockIdx.x * 32, by = blockIdx.y * 32;
    #pragma unroll
    for (int r = 0; r < 32; r += 8)
        tile[ty + r][tx] = f2bf(in[(size_t)(by + ty + r) * 1024 + bx + tx]);
    __syncthreads();
    #pragma unroll
    for (int r = 0; r < 32; r += 8)
        outp[(size_t)(bx + ty + r) * 1024 + by + tx] = tile[tx][ty + r];
}

// ---------------- bf16 1024x1024 transpose ---------------------------------
__global__ __launch_bounds__(256) void transpose1024(
    const unsigned short* __restrict__ in, unsigned short* __restrict__ outp) {
    __shared__ unsigned short tile[32][33];
    int tid = threadIdx.x;
    int tx = tid & 31, ty = tid >> 5;
    int bx = blockIdx.x * 32, by = blockIdx.y * 32;
    #pragma unroll
    for (int r = 0; r < 32; r += 8)
        tile[ty + r][tx] = in[(size_t)(by + ty + r) * 1024 + bx + tx];
    __syncthreads();
    #pragma unroll
    for (int r = 0; r < 32; r += 8)
        outp[(size_t)(bx + ty + r) * 1024 + by + tx] = tile[tx][ty + r];
}

// ---------------- fused transpose + LN1: tokens -> xbT ---------------------
// xbT[b][n][s] = bf16((tok[b*4096+s][n]-mu)*rs*g1[n]+b1[n]),  [4][1024][4096]
__global__ __launch_bounds__(256) void transln_kernel(
    const float* __restrict__ tok, const float* __restrict__ mu,
    const float* __restrict__ rs, const float* __restrict__ g,
    const float* __restrict__ bb, unsigned short* __restrict__ xbT) {
    __shared__ unsigned short tile[32][33];
    int tid = threadIdx.x;
    int tx = tid & 31, ty = tid >> 5;      // 32 x 8
    int s0 = blockIdx.x * 32;              // seq within batch
    int n0 = blockIdx.y * 32;              // feature
    int b  = blockIdx.z;
    float gv = g[n0 + tx], bv = bb[n0 + tx];
    #pragma unroll
    for (int r = 0; r < 32; r += 8) {
        int grow = (b << 12) + s0 + ty + r;
        float v = tok[(size_t)grow * 1024 + n0 + tx];
        tile[ty + r][tx] = f2bf((v - mu[grow]) * rs[grow] * gv + bv);
    }
    __syncthreads();
    #pragma unroll
    for (int r = 0; r < 32; r += 8)
        xbT[((size_t)b * 1024 + n0 + ty + r) * 4096 + s0 + tx] = tile[tx][ty + r];
}

// ---------------- small GEMM: Wfused = bf16(Wv @ Wo) -----------------------
__global__ __launch_bounds__(256) void gemm_small(
    const float* __restrict__ A32, const float* __restrict__ W32,
    unsigned short* __restrict__ C16) {
    const int K = 1024, N = 1024;
    __shared__ __align__(16) unsigned short As[64][40];
    __shared__ __align__(16) unsigned short Bs[64][40];
    int tid  = threadIdx.x;
    int lane = tid & 63, wv = tid >> 6;
    int lm   = lane & 15, quad = lane >> 4;
    int m0 = blockIdx.y * 64, n0 = blockIdx.x * 64;
    int srow = tid >> 2, scg = tid & 3;
    int bk   = tid >> 3, bn  = (tid & 7) * 8;

    f32x4 acc[4] = {};
    for (int k0 = 0; k0 < K; k0 += 32) {
        const float* ap = A32 + (size_t)(m0 + srow) * K + k0 + scg * 8;
        float4 p = *(const float4*)(ap);
        float4 q = *(const float4*)(ap + 4);
        union { uint4 u; unsigned short s[8]; } w;
        w.s[0]=f2bf(p.x); w.s[1]=f2bf(p.y); w.s[2]=f2bf(p.z); w.s[3]=f2bf(p.w);
        w.s[4]=f2bf(q.x); w.s[5]=f2bf(q.y); w.s[6]=f2bf(q.z); w.s[7]=f2bf(q.w);
        *(uint4*)&As[srow][scg * 8] = w.u;

        const float* wp = W32 + (size_t)(k0 + bk) * N + n0 + bn;
        float4 a = *(const float4*)wp, b = *(const float4*)(wp + 4);
        float wvv[8] = {a.x,a.y,a.z,a.w,b.x,b.y,b.z,b.w};
        #pragma unroll
        for (int e = 0; e < 8; ++e) Bs[bn + e][bk] = f2bf(wvv[e]);
        __syncthreads();
        bf16x8 af = *(const bf16x8*)&As[wv * 16 + lm][quad * 8];
        #pragma unroll
        for (int t = 0; t < 4; ++t) {
            bf16x8 bfr = *(const bf16x8*)&Bs[t * 16 + lm][quad * 8];
            acc[t] = __builtin_amdgcn_mfma_f32_16x16x32_bf16(af, bfr, acc[t], 0, 0, 0);
        }
        __syncthreads();
    }
    #pragma unroll
    for (int t = 0; t < 4; ++t) {
        int col = n0 + t * 16 + lm;
        #pragma unroll
        for (int r = 0; r < 4; ++r) {
            int row = m0 + wv * 16 + quad * 4 + r;
            C16[(size_t)row * N + col] = f2bf(acc[t][r]);
        }
    }
}

// ---------------- m97-style 128x128 GEMM: C = A[bf16] @ BT[bf16]^T ---------
template <bool EPI>
__global__ __launch_bounds__(256) void gemm128(
    const unsigned short* __restrict__ A, const unsigned short* __restrict__ BT,
    unsigned short* __restrict__ C16, float* __restrict__ Cres,
    const float* __restrict__ tok) {
    const int K = 1024, N = 1024;
    __shared__ __align__(16) unsigned short As[4096];  // 4 octets x 128 rows x 8
    __shared__ __align__(16) unsigned short Bs[4096];
    int tid = threadIdx.x, lane = tid & 63, wv = tid >> 6;
    int lm = lane & 15, quad = lane >> 4;
    int wr = wv >> 1, wc = wv & 1;
    int m0 = blockIdx.y * 128, n0 = blockIdx.x * 128;

    f32x4 acc[4][4] = {};

    const unsigned short* ga0 = A  + (size_t)(m0 + lane) * K + wv * 8;
    const unsigned short* ga1 = A  + (size_t)(m0 + 64 + lane) * K + wv * 8;
    const unsigned short* gb0 = BT + (size_t)(n0 + lane) * K + wv * 8;
    const unsigned short* gb1 = BT + (size_t)(n0 + 64 + lane) * K + wv * 8;
    unsigned short* la0 = &As[wv * 1024 + lane * 8];
    unsigned short* la1 = &As[wv * 1024 + 512 + lane * 8];
    unsigned short* lb0 = &Bs[wv * 1024 + lane * 8];
    unsigned short* lb1 = &Bs[wv * 1024 + 512 + lane * 8];

    for (int k0 = 0; k0 < K; k0 += 32) {
        gld_lds16(ga0 + k0, la0);
        gld_lds16(ga1 + k0, la1);
        gld_lds16(gb0 + k0, lb0);
        gld_lds16(gb1 + k0, lb1);
        __syncthreads();
        bf16x8 af[4], bfr[4];
        #pragma unroll
        for (int t = 0; t < 4; ++t) {
            af[t]  = *(const bf16x8*)&As[quad * 1024 + (wr * 64 + t * 16 + lm) * 8];
            bfr[t] = *(const bf16x8*)&Bs[quad * 1024 + (wc * 64 + t * 16 + lm) * 8];
        }
        #pragma unroll
        for (int mt = 0; mt < 4; ++mt)
            #pragma unroll
            for (int nt = 0; nt < 4; ++nt)
                acc[mt][nt] = __builtin_amdgcn_mfma_f32_16x16x32_bf16(
                    af[mt], bfr[nt], acc[mt][nt], 0, 0, 0);
        __syncthreads();
    }
    #pragma unroll
    for (int mt = 0; mt < 4; ++mt) {
        #pragma unroll
        for (int nt = 0; nt < 4; ++nt) {
            int col = n0 + wc * 64 + nt * 16 + lm;
            #pragma unroll
            for (int r = 0; r < 4; ++r) {
                int row = m0 + wr * 64 + mt * 16 + quad * 4 + r;
                size_t idx = (size_t)row * N + col;
                if (EPI) Cres[idx] = tok[idx] + 0.1f * acc[mt][nt][r];
                else     C16[idx]  = f2bf(acc[mt][nt][r]);
            }
        }
    }
}

// ---------------- MFMA sparse attention: 16 queries per block --------------
// Tiles (all 16-aligned, distinct): window [max(0,i0-256)..i0], strided
// i0-128t (t>=3, >=16), global tile 0 (if not already in window).
// Per-element mask applied when writing scores.  P kept bf16 in LDS.
// PV uses xbT [4][1024][4096] so B-frags are contiguous row reads.
#define NT_MAX 48
#define SCROW  776    // 48*16 + 8 pad (elems)
#define QROW   1032   // 1024 + 8 pad (elems)
__global__ __launch_bounds__(256) void attn16_kernel(
    const unsigned short* __restrict__ Q, const unsigned short* __restrict__ K,
    const unsigned short* __restrict__ XT, unsigned short* __restrict__ Ao) {
    __shared__ __align__(16) unsigned short Qs[16 * QROW];
    __shared__ __align__(16) unsigned short Ps[16 * SCROW];
    int tid = threadIdx.x, lane = tid & 63, wv = tid >> 6;
    int lm = lane & 15, quad = lane >> 4;
    int bx = blockIdx.x;
    int b  = bx >> 8;
    int i0 = (bx & 255) << 4;
    int rowbase = (b << 12) + i0;
    // tile bookkeeping (uniform)
    int wlo = i0 - 256; if (wlo < 0) wlo = 0;
    int nwin = ((i0 - wlo) >> 4) + 1;
    int tmax = (i0 - 16) / 128;              // trunc; i0=0 -> 0
    int nstr = tmax - 2; if (nstr < 0) nstr = 0;
    int nglob = (wlo > 0) ? 1 : 0;
    int ntiles = nwin + nstr + nglob;
    int ntp = (ntiles + 3) & ~3;

    // ---- stage Q tile (16 rows x 1024, padded rows) ----
    {
        int qr = tid >> 4, qc = (tid & 15) * 64;
        const unsigned short* src = Q + (size_t)(rowbase + qr) * 1024 + qc;
        unsigned short* dst = &Qs[qr * QROW + qc];
        #pragma unroll
        for (int e = 0; e < 8; ++e)
            *(uint4*)(dst + e * 8) = *(const uint4*)(src + e * 8);
    }
    __syncthreads();

    // ---- phase 1: score tiles (QK^T), masked write to Ps ----
    const unsigned short* Kbp = K + (((size_t)b << 12) << 10);
    for (int tg = wv * 4; tg < ntp; tg += 16) {
        f32x4 acc[4] = {};
        int tb[4];
        #pragma unroll
        for (int c = 0; c < 4; ++c) {
            int t = tg + c, base = 0;
            if (t < nwin) base = wlo + (t << 4);
            else if (t - nwin < nstr) base = i0 - 128 * (3 + (t - nwin));
            tb[c] = base;                     // global / padded -> 0
        }
        for (int k0 = 0; k0 < 1024; k0 += 32) {
            bf16x8 a = *(const bf16x8*)&Qs[lm * QROW + k0 + quad * 8];
            #pragma unroll
            for (int c = 0; c < 4; ++c) {
                bf16x8 bb = *(const bf16x8*)(Kbp +
                    (size_t)(tb[c] + lm) * 1024 + k0 + quad * 8);
                acc[c] = __builtin_amdgcn_mfma_f32_16x16x32_bf16(a, bb, acc[c], 0, 0, 0);
            }
        }
        #pragma unroll
        for (int c = 0; c < 4; ++c) {
            int t = tg + c;
            int j = tb[c] + lm;
            bool pad = (t >= ntiles);
            #pragma unroll
            for (int r = 0; r < 4; ++r) {
                int i = i0 + quad * 4 + r;
                int diff = i - j;
                bool ok = !pad && (j <= i) &&
                          (diff < 256 || (diff & 127) == 0 || j < 16);
                Ps[(quad * 4 + r) * SCROW + (t << 4) + lm] =
                    f2bf(ok ? acc[c][r] : -1e30f);
            }
        }
    }
    __syncthreads();

    // ---- phase 2: softmax on rows wv*4 .. wv*4+3 ----
    int ncol = ntp << 4;
    for (int q = wv * 4; q < wv * 4 + 4; ++q) {
        unsigned short* row = &Ps[q * SCROW];
        float mx = -1e30f;
        for (int c = lane; c < ncol; c += 64) mx = fmaxf(mx, b2f(row[c]));
        #pragma unroll
        for (int m = 32; m >= 1; m >>= 1) mx = fmaxf(mx, __shfl_xor(mx, m, 64));
        float sm = 0.f;
        for (int c = lane; c < ncol; c += 64)
            sm += __expf(SCALE_F * (b2f(row[c]) - mx));
        #pragma unroll
        for (int m = 32; m >= 1; m >>= 1) sm += __shfl_xor(sm, m, 64);
        float inv = 1.0f / sm;
        for (int c = lane; c < ncol; c += 64)
            row[c] = f2bf(__expf(SCALE_F * (b2f(row[c]) - mx)) * inv);
    }
    __syncthreads();

    // ---- phase 3: O = P @ X   (wave owns 256 cols) ----
    int n0w = wv * 256;
    const unsigned short* Xb = XT + ((size_t)b << 10) * 4096;
    f32x4 oacc[16] = {};
    int nch = ntp >> 1;
    for (int c = 0; c < nch; ++c) {
        int t0 = 2 * c, t1 = 2 * c + 1;
        int b0 = (t0 < nwin) ? wlo + (t0 << 4)
               : ((t0 - nwin < nstr) ? i0 - 128 * (3 + t0 - nwin) : 0);
        int b1 = (t1 < nwin) ? wlo + (t1 << 4)
               : ((t1 - nwin < nstr) ? i0 - 128 * (3 + t1 - nwin) : 0);
        bf16x8 a = *(const bf16x8*)&Ps[lm * SCROW + (c << 5) + quad * 8];
        int kb = (quad < 2) ? (b0 + quad * 8) : (b1 + (quad - 2) * 8);
        const unsigned short* xp = Xb + kb;
        #pragma unroll
        for (int nt = 0; nt < 16; ++nt) {
            bf16x8 bb = *(const bf16x8*)(xp + (size_t)(n0w + nt * 16 + lm) * 4096);
            oacc[nt] = __builtin_amdgcn_mfma_f32_16x16x32_bf16(a, bb, oacc[nt], 0, 0, 0);
        }
    }
    #pragma unroll
    for (int nt = 0; nt < 16; ++nt) {
        int col = n0w + nt * 16 + lm;
        #pragma unroll
        for (int r = 0; r < 4; ++r) {
            int row = rowbase + quad * 4 + r;
            Ao[(size_t)row * 1024 + col] = f2bf(oacc[nt][r]);
        }
    }
}

// ---------------------------------------------------------------------------
extern "C" void kernel_launch(void* const* d_in, const int* in_sizes, int n_in,
                              void* d_out, int out_size, void* d_ws, size_t ws_size,
                              hipStream_t stream) {
    const float* tokens = (const float*)d_in[0];
    const float* Wq = (const float*)d_in[1];
    const float* Wk = (const float*)d_in[2];
    const float* Wv = (const float*)d_in[3];
    const float* Wo = (const float*)d_in[4];
    const float* g1 = (const float*)d_in[5];
    const float* b1 = (const float*)d_in[6];
    const float* g2 = (const float*)d_in[7];
    const float* b2 = (const float*)d_in[8];
    float* out = (float*)d_out;
    char* ws = (char*)d_ws;

    // ws (41MB, same footprint as round 4):
    //   mu @0 (64KB), rs @64KB, WqT @1MB, WkT @3MB, Wfused @5MB, WfT @7MB,
    //   Q bf16 @9MB..41MB  -> attnX written in place
    // d_out (64MB fp32) as staging:
    //   xb bf16 @[0:32MB)  -> overwritten by xbT after Q/K gemms
    //   K  bf16 @[32:64MB)
    // then out-gemm overwrites all of d_out with fp32 residual; LN2 in place.
    const size_t MB = 1048576;
    float* mu = (float*)(ws);
    float* rs = (float*)(ws + 65536);
    unsigned short* WqT    = (unsigned short*)(ws + 1 * MB);
    unsigned short* WkT    = (unsigned short*)(ws + 3 * MB);
    unsigned short* Wfused = (unsigned short*)(ws + 5 * MB);
    unsigned short* WfT    = (unsigned short*)(ws + 7 * MB);
    unsigned short* Qb     = (unsigned short*)(ws + 9 * MB);
    unsigned short* xb     = (unsigned short*)d_out;
    unsigned short* xbT    = (unsigned short*)d_out;   // overwrites xb later
    unsigned short* Kb     = (unsigned short*)d_out + 16777216;
    unsigned short* attnX  = Qb;

    dim3 b256(256);
    const int ROWS = 4 * S_LEN;           // 16384
    dim3 tg(32, 32);
    dim3 gsmall(16, 16);
    dim3 g128(8, 128);                    // N/128 x M/128
    dim3 gtl(128, 32, 4);                 // transLN: s-tiles x n-tiles x batch

    // 1. LN1: stats + xb (row-major)
    ln_full_kernel<<<ROWS, b256, 0, stream>>>(tokens, mu, rs, g1, b1, xb);
    // 2. weight prep
    transpose_cvt<<<tg, b256, 0, stream>>>(Wq, WqT);
    transpose_cvt<<<tg, b256, 0, stream>>>(Wk, WkT);
    gemm_small<<<gsmall, b256, 0, stream>>>(Wv, Wo, Wfused);
    transpose1024<<<tg, b256, 0, stream>>>(Wfused, WfT);
    // 3. Q = xb@Wq, K = xb@Wk
    gemm128<false><<<g128, b256, 0, stream>>>(xb, WqT, Qb, nullptr, nullptr);
    gemm128<false><<<g128, b256, 0, stream>>>(xb, WkT, Kb, nullptr, nullptr);
    // 4. xbT = transpose(LN1(tokens)) per batch (overwrites xb; reads tokens)
    transln_kernel<<<gtl, b256, 0, stream>>>(tokens, mu, rs, g1, b1, xbT);
    // 5. MFMA sparse attention (attnX over Q)
    attn16_kernel<<<1024, b256, 0, stream>>>(Qb, Kb, xbT, attnX);
    // 6. out = tokens + 0.1*(attnX @ Wfused)
    gemm128<true><<<g128, b256, 0, stream>>>(attnX, WfT, nullptr, out, tokens);
    // 7. LN2 in place
    ln2_inplace_kernel<<<ROWS, b256, 0, stream>>>(out, g2, b2);
}